// Round 4
// baseline (115.159 us; speedup 1.0000x reference)
//
#include <hip/hip_runtime.h>
#include <hip/hip_bf16.h>
#include <math.h>

// Problem constants
#define HIDDEN 512
#define NHEADS 16
#define HDIM   32
#define BATCH  2
#define SEQ    1024
#define MROWS  (BATCH * SEQ)   // 2048

constexpr float LOG2_GAMMA = -0.15200309344504997f; // log2(0.9)

typedef __hip_bfloat16 bf16;
typedef __attribute__((ext_vector_type(8))) short short8;
typedef __attribute__((ext_vector_type(4))) float f32x4;

__device__ __forceinline__ unsigned short f2bf_bits(float f) {
    bf16 b = __float2bfloat16(f);
    return *(unsigned short*)&b;
}

// ---------------------------------------------------------------------------
// Fused prep: blocks 0-255 transpose+cast the 4 weights (fp32 [512 k][512 n]
// -> bf16 [n][512 k]); blocks 256-511 cast x fp32 -> bf16.
// ---------------------------------------------------------------------------
__global__ __launch_bounds__(256) void prep(
    const float* __restrict__ x,
    const float* __restrict__ qw, const float* __restrict__ kw,
    const float* __restrict__ vw, const float* __restrict__ ow,
    bf16* __restrict__ xb, bf16* __restrict__ wqkvt, bf16* __restrict__ wot)
{
    const int blk = blockIdx.x, tid = threadIdx.x;
    if (blk < 256) {
        const int widx = blk >> 6;
        const int tile = blk & 63;
        const int tk = (tile & 7) * 64, tn = (tile >> 3) * 64;
        const float* w = widx == 0 ? qw : widx == 1 ? kw : widx == 2 ? vw : ow;
        __shared__ float t[64][65];
        #pragma unroll
        for (int u = 0; u < 4; ++u) {
            const int r = u * 16 + (tid >> 4);
            const int c = (tid & 15) * 4;
            float4 v = *(const float4*)&w[(size_t)(tk + r) * 512 + tn + c];
            t[r][c + 0] = v.x; t[r][c + 1] = v.y; t[r][c + 2] = v.z; t[r][c + 3] = v.w;
        }
        __syncthreads();
        #pragma unroll
        for (int u = 0; u < 2; ++u) {
            const int rr = u * 32 + (tid >> 3);
            const int cc = (tid & 7) * 8;
            alignas(16) unsigned short tmp[8];
            #pragma unroll
            for (int i = 0; i < 8; ++i) tmp[i] = f2bf_bits(t[cc + i][rr]);
            bf16* dst = (widx < 3)
                ? &wqkvt[((size_t)widx * 512 + tn + rr) * 512 + tk + cc]
                : &wot[(size_t)(tn + rr) * 512 + tk + cc];
            *(short8*)dst = *(short8*)tmp;
        }
    } else {
        #pragma unroll
        for (int u = 0; u < 4; ++u) {
            const int idx = (blk - 256) * 1024 + u * 256 + tid;
            float4 v = ((const float4*)x)[idx];
            unsigned pk0 = (unsigned)f2bf_bits(v.x) | ((unsigned)f2bf_bits(v.y) << 16);
            unsigned pk1 = (unsigned)f2bf_bits(v.z) | ((unsigned)f2bf_bits(v.w) << 16);
            uint2 pk = {pk0, pk1};
            *(uint2*)&xb[(size_t)idx * 4] = pk;
        }
    }
}

// ---------------------------------------------------------------------------
// Direct-from-global MFMA GEMM (no LDS, no barriers). K=512.
// Block 64x64: 4 waves 2x2, wave tile 32x32 = TM2 x TN2 of 16x16x32.
// Fragments load straight from row-major K-contiguous A[m][k], Bt[n][k]
// (one global_load_dwordx4 each; L2-resident operands).
// EPI=1 (QKV): bf16 out, segmented bias + gamma row-scale folded in.
// EPI=0 (out-proj): fp32 out + bias.
// ---------------------------------------------------------------------------
template<int EPI>
__global__ __launch_bounds__(256) void gemm_direct(
    const bf16* __restrict__ A, const bf16* __restrict__ Bt,
    const float* __restrict__ b0, const float* __restrict__ b1,
    const float* __restrict__ b2,
    float* __restrict__ Cf, bf16* __restrict__ Cb, int ldc)
{
    constexpr int K = 512;
    const int tid = threadIdx.x;
    const int wave = tid >> 6, lane = tid & 63;
    const int fr = lane & 15, quad = lane >> 4;
    const int m0 = blockIdx.y * 64 + (wave >> 1) * 32;
    const int n0 = blockIdx.x * 64 + (wave & 1) * 32;

    const bf16* pa0 = &A[(size_t)(m0 + fr) * K + quad * 8];
    const bf16* pa1 = pa0 + (size_t)16 * K;
    const bf16* pb0 = &Bt[(size_t)(n0 + fr) * K + quad * 8];
    const bf16* pb1 = pb0 + (size_t)16 * K;

    f32x4 acc00 = {}, acc01 = {}, acc10 = {}, acc11 = {};
    short8 ca0 = *(const short8*)pa0;
    short8 ca1 = *(const short8*)pa1;
    short8 cb0 = *(const short8*)pb0;
    short8 cb1 = *(const short8*)pb1;

    #pragma unroll
    for (int ks = 0; ks < 16; ++ks) {
        short8 na0, na1, nb0, nb1;
        if (ks < 15) {   // statically resolved under full unroll
            na0 = *(const short8*)(pa0 + (ks + 1) * 32);
            na1 = *(const short8*)(pa1 + (ks + 1) * 32);
            nb0 = *(const short8*)(pb0 + (ks + 1) * 32);
            nb1 = *(const short8*)(pb1 + (ks + 1) * 32);
        }
        acc00 = __builtin_amdgcn_mfma_f32_16x16x32_bf16(ca0, cb0, acc00, 0, 0, 0);
        acc01 = __builtin_amdgcn_mfma_f32_16x16x32_bf16(ca0, cb1, acc01, 0, 0, 0);
        acc10 = __builtin_amdgcn_mfma_f32_16x16x32_bf16(ca1, cb0, acc10, 0, 0, 0);
        acc11 = __builtin_amdgcn_mfma_f32_16x16x32_bf16(ca1, cb1, acc11, 0, 0, 0);
        ca0 = na0; ca1 = na1; cb0 = nb0; cb1 = nb1;
    }

    f32x4 acc[2][2] = {{acc00, acc01}, {acc10, acc11}};

    // Epilogue. C/D layout: col(n)=lane&15, row(m)=quad*4+reg.
    if (EPI == 1) {
        const int seg = (blockIdx.x * 64) >> 9;   // q/k/v segment (block-uniform)
        const float* bp = seg == 0 ? b0 : seg == 1 ? b1 : b2;
        const float sgn = seg == 0 ? 0.5f : seg == 1 ? -0.5f : 0.0f;
        #pragma unroll
        for (int i = 0; i < 2; ++i) {
            const int mrow = m0 + i * 16 + quad * 4;
            float sc[4];
            #pragma unroll
            for (int r = 0; r < 4; ++r)
                sc[r] = exp2f((float)((mrow + r) & 63) * (sgn * LOG2_GAMMA));
            #pragma unroll
            for (int j = 0; j < 2; ++j) {
                const int n = n0 + j * 16 + fr;
                const float bv = bp[n & 511];
                #pragma unroll
                for (int r = 0; r < 4; ++r) {
                    unsigned short h = f2bf_bits((acc[i][j][r] + bv) * sc[r]);
                    *(unsigned short*)&Cb[(size_t)(mrow + r) * ldc + n] = h;
                }
            }
        }
    } else {
        #pragma unroll
        for (int i = 0; i < 2; ++i) {
            const int mrow = m0 + i * 16 + quad * 4;
            #pragma unroll
            for (int j = 0; j < 2; ++j) {
                const int n = n0 + j * 16 + fr;
                const float bv = b0[n];
                #pragma unroll
                for (int r = 0; r < 4; ++r)
                    Cf[(size_t)(mrow + r) * ldc + n] = acc[i][j][r] + bv;
            }
        }
    }
}

// ---------------------------------------------------------------------------
// MFMA power attention. Decay row-scales pre-folded into q,k. Q/K fragments
// load directly from global (L2-resident qkv); only V^T and P use LDS.
// ---------------------------------------------------------------------------
__global__ __launch_bounds__(256) void power_attn_mfma(
    const bf16* __restrict__ qkv, bf16* __restrict__ atc)
{
    __shared__ alignas(16) short Vt[32 * 80];   // V transposed [d][s], stride 80
    __shared__ alignas(16) short Ps[64 * 72];   // P [t][s], stride 72

    const int tid = threadIdx.x, wave = tid >> 6, lane = tid & 63;
    const int chunk = blockIdx.x, bh = blockIdx.y;
    const int b = bh >> 4, h = bh & 15;
    const int mb = b * SEQ + chunk * 64;
    const int fr = lane & 15, quad = lane >> 4;

    // Q fragment: wave w owns rows w*16..w*16+15 (A-layout: m=fr, k=quad*8+j)
    short8 aq = *(const short8*)&qkv[(size_t)(mb + wave * 16 + fr) * 1536 + h * 32 + quad * 8];

    f32x4 o0 = {}, o1 = {};
    const int jstart = chunk >= 2 ? chunk - 2 : 0;   // gamma^129 ~ 1e-6

    for (int j = jstart; j <= chunk; ++j) {
        __syncthreads();   // protect Vt from previous iteration's readers
        const int sb = b * SEQ + j * 64;
        if (tid < 128) {   // transpose-stage V: pairs of s packed as b32 writes
            const int p = tid >> 2, s = p * 2, dbase = (tid & 3) * 8;
            const short* g = (const short*)&qkv[(size_t)(sb + s) * 1536 + 1024 + h * 32 + dbase];
            short8 v0 = *(const short8*)g;
            short8 v1 = *(const short8*)(g + 1536);
            #pragma unroll
            for (int i = 0; i < 8; ++i) {
                unsigned pk = (unsigned)(unsigned short)v0[i]
                            | ((unsigned)(unsigned short)v1[i] << 16);
                *(unsigned*)&Vt[(dbase + i) * 80 + s] = pk;
            }
        }
        __syncthreads();

        // S = Q @ K^T : per wave 16x64, K-frags direct from global
        f32x4 sAcc[4] = {};
        #pragma unroll
        for (int nt = 0; nt < 4; ++nt) {
            short8 bk = *(const short8*)&qkv[(size_t)(sb + nt * 16 + fr) * 1536 + 512 + h * 32 + quad * 8];
            sAcc[nt] = __builtin_amdgcn_mfma_f32_16x16x32_bf16(aq, bk, sAcc[nt], 0, 0, 0);
        }

        const int dj = chunk - j;
        const float sj = exp2f(64.0f * (float)dj * LOG2_GAMMA);
        const int tbase = wave * 16 + quad * 4;
        #pragma unroll
        for (int nt = 0; nt < 4; ++nt) {
            const int s_l = nt * 16 + fr;
            #pragma unroll
            for (int r = 0; r < 4; ++r) {
                const int t_l = tbase + r;
                float pv = sAcc[nt][r];
                pv = pv * pv * sj;
                if (dj == 0 && s_l > t_l) pv = 0.0f;
                Ps[t_l * 72 + s_l] = (short)f2bf_bits(pv);
            }
        }
        // same-wave write->read (wave reads only its own 16 Ps rows)
        short8 a0 = *(const short8*)&Ps[(wave * 16 + fr) * 72 + quad * 8];
        short8 a1 = *(const short8*)&Ps[(wave * 16 + fr) * 72 + 32 + quad * 8];
        short8 b00 = *(const short8*)&Vt[fr * 80 + quad * 8];
        short8 b01 = *(const short8*)&Vt[fr * 80 + 32 + quad * 8];
        short8 b10 = *(const short8*)&Vt[(16 + fr) * 80 + quad * 8];
        short8 b11 = *(const short8*)&Vt[(16 + fr) * 80 + 32 + quad * 8];
        o0 = __builtin_amdgcn_mfma_f32_16x16x32_bf16(a0, b00, o0, 0, 0, 0);
        o0 = __builtin_amdgcn_mfma_f32_16x16x32_bf16(a1, b01, o0, 0, 0, 0);
        o1 = __builtin_amdgcn_mfma_f32_16x16x32_bf16(a0, b10, o1, 0, 0, 0);
        o1 = __builtin_amdgcn_mfma_f32_16x16x32_bf16(a1, b11, o1, 0, 0, 0);
    }

    #pragma unroll
    for (int r = 0; r < 4; ++r) {
        const size_t row = mb + wave * 16 + quad * 4 + r;
        const int col = h * 32 + fr;
        *(unsigned short*)&atc[row * 512 + col]      = f2bf_bits(o0[r]);
        *(unsigned short*)&atc[row * 512 + col + 16] = f2bf_bits(o1[r]);
    }
}

// ---------------------------------------------------------------------------
extern "C" void kernel_launch(void* const* d_in, const int* in_sizes, int n_in,
                              void* d_out, int out_size, void* d_ws, size_t ws_size,
                              hipStream_t stream)
{
    const float* x  = (const float*)d_in[0];
    const float* qw = (const float*)d_in[1];
    const float* qb = (const float*)d_in[2];
    const float* kw = (const float*)d_in[3];
    const float* kb = (const float*)d_in[4];
    const float* vw = (const float*)d_in[5];
    const float* vb = (const float*)d_in[6];
    const float* ow = (const float*)d_in[7];
    const float* ob = (const float*)d_in[8];
    float* out = (float*)d_out;

    char* w = (char*)d_ws;
    bf16* xb    = (bf16*)(w);                                    // 2 MB   [2048][512]
    bf16* wqkvt = (bf16*)(w + (2ull  << 20));                    // 1.5 MB [1536][512]
    bf16* wot   = (bf16*)(w + (2ull  << 20) + (1536ull << 10));  // 0.5 MB [512][512]
    bf16* qkvb  = (bf16*)(w + (4ull  << 20));                    // 6 MB   [2048][1536]
    bf16* atc   = (bf16*)(w + (10ull << 20));                    // 2 MB   [2048][512]

    prep<<<512, 256, 0, stream>>>(x, qw, kw, vw, ow, xb, wqkvt, wot);

    // QKV GEMM: [2048][512] x [1536][512]^T -> bf16 [2048][1536] (scaled)
    gemm_direct<1><<<dim3(1536 / 64, MROWS / 64), 256, 0, stream>>>(
        xb, wqkvt, qb, kb, vb, nullptr, qkvb, 1536);

    power_attn_mfma<<<dim3(SEQ / 64, BATCH * NHEADS), 256, 0, stream>>>(qkvb, atc);

    // Output GEMM: [2048][512] x [512][512]^T -> fp32 out
    gemm_direct<0><<<dim3(512 / 64, MROWS / 64), 256, 0, stream>>>(
        atc, wot, ob, nullptr, nullptr, out, nullptr, 512);
}

// Round 5
// 97.717 us; speedup vs baseline: 1.1785x; 1.1785x over previous
//
#include <hip/hip_runtime.h>
#include <hip/hip_bf16.h>
#include <math.h>

// Problem constants
#define HIDDEN 512
#define NHEADS 16
#define HDIM   32
#define BATCH  2
#define SEQ    1024
#define MROWS  (BATCH * SEQ)   // 2048

constexpr float LOG2_GAMMA = -0.15200309344504997f; // log2(0.9)

typedef __hip_bfloat16 bf16;
typedef __attribute__((ext_vector_type(8))) short short8;
typedef __attribute__((ext_vector_type(4))) float f32x4;

__device__ __forceinline__ void async16(const void* g, void* l) {
    __builtin_amdgcn_global_load_lds(
        (const __attribute__((address_space(1))) void*)g,
        (__attribute__((address_space(3))) void*)l, 16, 0, 0);
}

__device__ __forceinline__ unsigned short f2bf_bits(float f) {
    bf16 b = __float2bfloat16(f);
    return *(unsigned short*)&b;
}

// ---------------------------------------------------------------------------
// Fused prep: blocks 0-255 transpose+cast the 4 weights (fp32 [512 k][512 n]
// -> bf16 [n][512 k]); blocks 256-511 cast x fp32 -> bf16.
// ---------------------------------------------------------------------------
__global__ __launch_bounds__(256) void prep(
    const float* __restrict__ x,
    const float* __restrict__ qw, const float* __restrict__ kw,
    const float* __restrict__ vw, const float* __restrict__ ow,
    bf16* __restrict__ xb, bf16* __restrict__ wqkvt, bf16* __restrict__ wot)
{
    const int blk = blockIdx.x, tid = threadIdx.x;
    if (blk < 256) {
        const int widx = blk >> 6;
        const int tile = blk & 63;
        const int tk = (tile & 7) * 64, tn = (tile >> 3) * 64;
        const float* w = widx == 0 ? qw : widx == 1 ? kw : widx == 2 ? vw : ow;
        __shared__ float t[64][65];
        #pragma unroll
        for (int u = 0; u < 4; ++u) {
            const int r = u * 16 + (tid >> 4);
            const int c = (tid & 15) * 4;
            float4 v = *(const float4*)&w[(size_t)(tk + r) * 512 + tn + c];
            t[r][c + 0] = v.x; t[r][c + 1] = v.y; t[r][c + 2] = v.z; t[r][c + 3] = v.w;
        }
        __syncthreads();
        #pragma unroll
        for (int u = 0; u < 2; ++u) {
            const int rr = u * 32 + (tid >> 3);
            const int cc = (tid & 7) * 8;
            alignas(16) unsigned short tmp[8];
            #pragma unroll
            for (int i = 0; i < 8; ++i) tmp[i] = f2bf_bits(t[cc + i][rr]);
            bf16* dst = (widx < 3)
                ? &wqkvt[((size_t)widx * 512 + tn + rr) * 512 + tk + cc]
                : &wot[(size_t)(tn + rr) * 512 + tk + cc];
            *(short8*)dst = *(short8*)tmp;
        }
    } else {
        #pragma unroll
        for (int u = 0; u < 4; ++u) {
            const int idx = (blk - 256) * 1024 + u * 256 + tid;
            float4 v = ((const float4*)x)[idx];
            unsigned pk0 = (unsigned)f2bf_bits(v.x) | ((unsigned)f2bf_bits(v.y) << 16);
            unsigned pk1 = (unsigned)f2bf_bits(v.z) | ((unsigned)f2bf_bits(v.w) << 16);
            uint2 pk = {pk0, pk1};
            *(uint2*)&xb[(size_t)idx * 4] = pk;
        }
    }
}

// ---------------------------------------------------------------------------
// Persistent-B MFMA GEMM: block owns a 64-column B-tile for ALL of K=512,
// staged once into LDS (padded rows, 2-way-max bank aliasing), then a
// fully-unrolled, barrier-free K-sweep: A-frags stream direct from global
// (row-major K-contiguous bf16), B-frags from LDS. No per-K-step barrier.
// MS = rows per block (wave w owns rows [w*MS/4, ...)). TM = MS/64.
// EPI=1 (QKV): bf16 out, segmented bias + gamma row-scale. EPI=0: fp32+bias.
// ---------------------------------------------------------------------------
template<int MS, int EPI>
__global__ __launch_bounds__(256) void gemm_persistB(
    const bf16* __restrict__ A, const bf16* __restrict__ Bt,
    const float* __restrict__ b0, const float* __restrict__ b1,
    const float* __restrict__ b2,
    float* __restrict__ Cf, bf16* __restrict__ Cb, int ldc)
{
    constexpr int K = 512;
    constexpr int LDB = 520;              // +8 shorts pad -> 2-way aliasing only
    constexpr int TM = MS / 64;
    __shared__ alignas(16) short Bs[64 * LDB];   // 66.5 KB -> 2 blocks/CU

    const int tid = threadIdx.x;
    const int wave = tid >> 6, lane = tid & 63;
    const int fr = lane & 15, quad = lane >> 4;
    const int n0 = blockIdx.x * 64;
    const int m0 = blockIdx.y * MS;

    // ---- stage B once: row = 1 KB contiguous = one async16 wave-instr
    #pragma unroll
    for (int i = 0; i < 16; ++i) {
        const int row = wave * 16 + i;
        async16(&Bt[(size_t)(n0 + row) * K + lane * 8], &Bs[row * LDB]);
    }
    __syncthreads();   // single barrier; vmcnt drain folded in here

    const bf16* pa = &A[(size_t)(m0 + wave * (MS / 4) + fr) * K + quad * 8];

    f32x4 acc[TM][4] = {};
    #pragma unroll
    for (int ks = 0; ks < 16; ++ks) {
        short8 bfrag[4];
        #pragma unroll
        for (int j = 0; j < 4; ++j)
            bfrag[j] = *(const short8*)&Bs[(j * 16 + fr) * LDB + ks * 32 + quad * 8];
        #pragma unroll
        for (int i = 0; i < TM; ++i) {
            short8 af = *(const short8*)(pa + (size_t)i * 16 * K + ks * 32);
            #pragma unroll
            for (int j = 0; j < 4; ++j)
                acc[i][j] = __builtin_amdgcn_mfma_f32_16x16x32_bf16(
                    af, bfrag[j], acc[i][j], 0, 0, 0);
        }
    }

    // Epilogue. C/D layout: col(n)=lane&15, row(m)=quad*4+reg.
    if (EPI == 1) {
        const int seg = n0 >> 9;   // q/k/v segment (block-uniform)
        const float* bp = seg == 0 ? b0 : seg == 1 ? b1 : b2;
        const float sgn = seg == 0 ? 0.5f : seg == 1 ? -0.5f : 0.0f;
        #pragma unroll
        for (int i = 0; i < TM; ++i) {
            const int mrow = m0 + wave * (MS / 4) + i * 16 + quad * 4;
            float sc[4];
            #pragma unroll
            for (int r = 0; r < 4; ++r)
                sc[r] = exp2f((float)((mrow + r) & 63) * (sgn * LOG2_GAMMA));
            #pragma unroll
            for (int j = 0; j < 4; ++j) {
                const int n = n0 + j * 16 + fr;
                const float bv = bp[n & 511];
                #pragma unroll
                for (int r = 0; r < 4; ++r) {
                    unsigned short h = f2bf_bits((acc[i][j][r] + bv) * sc[r]);
                    *(unsigned short*)&Cb[(size_t)(mrow + r) * ldc + n] = h;
                }
            }
        }
    } else {
        #pragma unroll
        for (int i = 0; i < TM; ++i) {
            const int mrow = m0 + wave * (MS / 4) + i * 16 + quad * 4;
            #pragma unroll
            for (int j = 0; j < 4; ++j) {
                const int n = n0 + j * 16 + fr;
                const float bv = b0[n];
                #pragma unroll
                for (int r = 0; r < 4; ++r)
                    Cf[(size_t)(mrow + r) * ldc + n] = acc[i][j][r] + bv;
            }
        }
    }
}

// ---------------------------------------------------------------------------
// MFMA power attention (R3 version). Decay row-scales pre-folded into q,k by
// the QKV GEMM; here S = Q@K^T, P = S^2 * gamma^(64*dj) + causal mask, LDS
// round-trip to A-layout, O += P@V.
// ---------------------------------------------------------------------------
__global__ __launch_bounds__(256) void power_attn_mfma(
    const bf16* __restrict__ qkv, bf16* __restrict__ atc)
{
    __shared__ alignas(16) short Qs[64 * 32];
    __shared__ alignas(16) short Ks[64 * 32];
    __shared__ alignas(16) short Vt[32 * 80];   // V^T [d][s], stride 80
    __shared__ alignas(16) short Ps[64 * 72];   // P [t][s], stride 72

    const int tid = threadIdx.x, wave = tid >> 6, lane = tid & 63;
    const int chunk = blockIdx.x, bh = blockIdx.y;
    const int b = bh >> 4, h = bh & 15;
    const int mb = b * SEQ + chunk * 64;
    const int fr = lane & 15, quad = lane >> 4;

    async16(&qkv[(size_t)(mb + wave * 16 + (lane >> 2)) * 1536 + h * 32 + (lane & 3) * 8],
            &Qs[wave * 512]);

    f32x4 o0 = {}, o1 = {};
    const int jstart = chunk >= 2 ? chunk - 2 : 0;   // gamma^129 ~ 1e-6

    for (int j = jstart; j <= chunk; ++j) {
        __syncthreads();
        const int sb = b * SEQ + j * 64;
        async16(&qkv[(size_t)(sb + wave * 16 + (lane >> 2)) * 1536 + 512 + h * 32 + (lane & 3) * 8],
                &Ks[wave * 512]);
        if (tid < 128) {   // transpose-stage V: pairs of s packed as b32 writes
            const int p = tid >> 2, s = p * 2, dbase = (tid & 3) * 8;
            const short* g = (const short*)&qkv[(size_t)(sb + s) * 1536 + 1024 + h * 32 + dbase];
            short8 v0 = *(const short8*)g;
            short8 v1 = *(const short8*)(g + 1536);
            #pragma unroll
            for (int i = 0; i < 8; ++i) {
                unsigned pk = (unsigned)(unsigned short)v0[i]
                            | ((unsigned)(unsigned short)v1[i] << 16);
                *(unsigned*)&Vt[(dbase + i) * 80 + s] = pk;
            }
        }
        __syncthreads();

        short8 aq = *(const short8*)&Qs[(wave * 16 + fr) * 32 + quad * 8];
        f32x4 sAcc[4] = {};
        #pragma unroll
        for (int nt = 0; nt < 4; ++nt) {
            short8 bk = *(const short8*)&Ks[(nt * 16 + fr) * 32 + quad * 8];
            sAcc[nt] = __builtin_amdgcn_mfma_f32_16x16x32_bf16(aq, bk, sAcc[nt], 0, 0, 0);
        }

        const int dj = chunk - j;
        const float sj = exp2f(64.0f * (float)dj * LOG2_GAMMA);
        const int tbase = wave * 16 + quad * 4;
        #pragma unroll
        for (int nt = 0; nt < 4; ++nt) {
            const int s_l = nt * 16 + fr;
            #pragma unroll
            for (int r = 0; r < 4; ++r) {
                const int t_l = tbase + r;
                float pv = sAcc[nt][r];
                pv = pv * pv * sj;
                if (dj == 0 && s_l > t_l) pv = 0.0f;
                Ps[t_l * 72 + s_l] = (short)f2bf_bits(pv);
            }
        }
        short8 a0 = *(const short8*)&Ps[(wave * 16 + fr) * 72 + quad * 8];
        short8 a1 = *(const short8*)&Ps[(wave * 16 + fr) * 72 + 32 + quad * 8];
        short8 b00 = *(const short8*)&Vt[fr * 80 + quad * 8];
        short8 b01 = *(const short8*)&Vt[fr * 80 + 32 + quad * 8];
        short8 b10 = *(const short8*)&Vt[(16 + fr) * 80 + quad * 8];
        short8 b11 = *(const short8*)&Vt[(16 + fr) * 80 + 32 + quad * 8];
        o0 = __builtin_amdgcn_mfma_f32_16x16x32_bf16(a0, b00, o0, 0, 0, 0);
        o0 = __builtin_amdgcn_mfma_f32_16x16x32_bf16(a1, b01, o0, 0, 0, 0);
        o1 = __builtin_amdgcn_mfma_f32_16x16x32_bf16(a0, b10, o1, 0, 0, 0);
        o1 = __builtin_amdgcn_mfma_f32_16x16x32_bf16(a1, b11, o1, 0, 0, 0);
    }

    #pragma unroll
    for (int r = 0; r < 4; ++r) {
        const size_t row = mb + wave * 16 + quad * 4 + r;
        const int col = h * 32 + fr;
        *(unsigned short*)&atc[row * 512 + col]      = f2bf_bits(o0[r]);
        *(unsigned short*)&atc[row * 512 + col + 16] = f2bf_bits(o1[r]);
    }
}

// ---------------------------------------------------------------------------
extern "C" void kernel_launch(void* const* d_in, const int* in_sizes, int n_in,
                              void* d_out, int out_size, void* d_ws, size_t ws_size,
                              hipStream_t stream)
{
    const float* x  = (const float*)d_in[0];
    const float* qw = (const float*)d_in[1];
    const float* qb = (const float*)d_in[2];
    const float* kw = (const float*)d_in[3];
    const float* kb = (const float*)d_in[4];
    const float* vw = (const float*)d_in[5];
    const float* vb = (const float*)d_in[6];
    const float* ow = (const float*)d_in[7];
    const float* ob = (const float*)d_in[8];
    float* out = (float*)d_out;

    char* w = (char*)d_ws;
    bf16* xb    = (bf16*)(w);                                    // 2 MB   [2048][512]
    bf16* wqkvt = (bf16*)(w + (2ull  << 20));                    // 1.5 MB [1536][512]
    bf16* wot   = (bf16*)(w + (2ull  << 20) + (1536ull << 10));  // 0.5 MB [512][512]
    bf16* qkvb  = (bf16*)(w + (4ull  << 20));                    // 6 MB   [2048][1536]
    bf16* atc   = (bf16*)(w + (10ull << 20));                    // 2 MB   [2048][512]

    prep<<<512, 256, 0, stream>>>(x, qw, kw, vw, ow, xb, wqkvt, wot);

    // QKV GEMM: [2048][512] x [1536][512]^T -> bf16 [2048][1536] (scaled)
    gemm_persistB<128, 1><<<dim3(1536 / 64, MROWS / 128), 256, 0, stream>>>(
        xb, wqkvt, qb, kb, vb, nullptr, qkvb, 1536);

    power_attn_mfma<<<dim3(SEQ / 64, BATCH * NHEADS), 256, 0, stream>>>(qkvb, atc);

    // Output GEMM: [2048][512] x [512][512]^T -> fp32 out
    gemm_persistB<64, 0><<<dim3(512 / 64, MROWS / 64), 256, 0, stream>>>(
        atc, wot, ob, nullptr, nullptr, out, nullptr, 512);
}